// Round 22
// baseline (959.535 us; speedup 1.0000x reference)
//
#include <hip/hip_runtime.h>
#include <hip/hip_bf16.h>

#define D_ 2048
#define H_ 16
#define KVH_ 4
#define HD_ 128
#define E_ 32
#define TOPK_ 8
#define F_ 768
#define NB_ 2
#define SS_ 1024
#define NT_ 2048
#define NPAIR_ 16384

typedef __attribute__((ext_vector_type(8))) short short8;
typedef __attribute__((ext_vector_type(4))) float floatx4;
typedef __attribute__((ext_vector_type(4))) unsigned int uintx4;
typedef __attribute__((ext_vector_type(4))) unsigned short ushortx4;

__device__ __forceinline__ unsigned short f2bf(float f) {
  union { float f; unsigned u; } v; v.f = f;
  unsigned r = v.u + 0x7FFFu + ((v.u >> 16) & 1u);
  return (unsigned short)(r >> 16);
}
__device__ __forceinline__ float bf2f(unsigned short h) {
  union { unsigned u; float f; } v; v.u = ((unsigned)h) << 16;
  return v.f;
}
__device__ __forceinline__ void split2(float v, unsigned short& hi, unsigned short& lo) {
  unsigned short h = f2bf(v);
  hi = h;
  lo = f2bf(v - bf2f(h));
}
// async global->LDS, 16B per lane; LDS dest = wave-uniform base + lane*16
__device__ __forceinline__ void gload16(const unsigned short* g, unsigned short* l) {
  __builtin_amdgcn_global_load_lds(
      (const __attribute__((address_space(1))) unsigned int*)g,
      (__attribute__((address_space(3))) unsigned int*)l, 16, 0, 0);
}

// ---------------- weight transpose + convert: fp32 [R][C] -> bf16 [C][R] ----------------
__global__ __launch_bounds__(256) void tconv_kernel(const float* __restrict__ src,
                                                    unsigned short* __restrict__ dst,
                                                    int R, int C) {
  size_t off = (size_t)blockIdx.z * R * C;
  src += off; dst += off;
  __shared__ float t[32][33];
  int c0 = blockIdx.x * 32, r0 = blockIdx.y * 32;
  int row = threadIdx.x >> 3, c4 = (threadIdx.x & 7) * 4;
  float4 v = *(const float4*)(src + (size_t)(r0 + row) * C + c0 + c4);
  t[row][c4 + 0] = v.x; t[row][c4 + 1] = v.y; t[row][c4 + 2] = v.z; t[row][c4 + 3] = v.w;
  __syncthreads();
  ushortx4 o = { f2bf(t[c4 + 0][row]), f2bf(t[c4 + 1][row]),
                 f2bf(t[c4 + 2][row]), f2bf(t[c4 + 3][row]) };
  *(ushortx4*)(dst + (size_t)(c0 + row) * R + r0 + c4) = o;
}

// ---------------- fused gate+up transpose+convert: z<32 -> gate expert z, else up expert z-32 --
__global__ __launch_bounds__(256) void tconv_gu_kernel(const float* __restrict__ gp,
                                                       const float* __restrict__ up,
                                                       unsigned short* __restrict__ gT,
                                                       unsigned short* __restrict__ uT) {
  int z = blockIdx.z;
  const float* src;
  unsigned short* dst;
  if (z < 32) { src = gp + (size_t)z * 2048 * 768; dst = gT + (size_t)z * 2048 * 768; }
  else        { src = up + (size_t)(z - 32) * 2048 * 768; dst = uT + (size_t)(z - 32) * 2048 * 768; }
  __shared__ float t[32][33];
  int c0 = blockIdx.x * 32, r0 = blockIdx.y * 32;
  int row = threadIdx.x >> 3, c4 = (threadIdx.x & 7) * 4;
  float4 v = *(const float4*)(src + (size_t)(r0 + row) * 768 + c0 + c4);
  t[row][c4 + 0] = v.x; t[row][c4 + 1] = v.y; t[row][c4 + 2] = v.z; t[row][c4 + 3] = v.w;
  __syncthreads();
  ushortx4 o = { f2bf(t[c4 + 0][row]), f2bf(t[c4 + 1][row]),
                 f2bf(t[c4 + 2][row]), f2bf(t[c4 + 3][row]) };
  *(ushortx4*)(dst + (size_t)(c0 + row) * 2048 + r0 + c4) = o;
}

// ---------------- weight transpose + split: fp32 [R][C] -> hi/lo bf16 [C][R] ----------------
__global__ __launch_bounds__(256) void tsplit_kernel(const float* __restrict__ src,
                                                     unsigned short* __restrict__ dhi,
                                                     unsigned short* __restrict__ dlo,
                                                     int R, int C) {
  __shared__ float t[32][33];
  int c0 = blockIdx.x * 32, r0 = blockIdx.y * 32;
  int row = threadIdx.x >> 3, c4 = (threadIdx.x & 7) * 4;
  float4 v = *(const float4*)(src + (size_t)(r0 + row) * C + c0 + c4);
  t[row][c4 + 0] = v.x; t[row][c4 + 1] = v.y; t[row][c4 + 2] = v.z; t[row][c4 + 3] = v.w;
  __syncthreads();
  ushortx4 oh, ol;
  #pragma unroll
  for (int i = 0; i < 4; ++i) {
    unsigned short hi, lo;
    split2(t[c4 + i][row], hi, lo);
    oh[i] = hi; ol[i] = lo;
  }
  size_t didx = (size_t)(c0 + row) * R + r0 + c4;
  *(ushortx4*)(dhi + didx) = oh;
  *(ushortx4*)(dlo + didx) = ol;
}

// -------- fused QKV transpose+split into packed [3072][2048]: x<64 Q, <80 K, else V --------
__global__ __launch_bounds__(256) void tsplit_qkv_kernel(const float* __restrict__ q_w,
                                                         const float* __restrict__ k_w,
                                                         const float* __restrict__ v_w,
                                                         unsigned short* __restrict__ dhi,
                                                         unsigned short* __restrict__ dlo) {
  int bx = blockIdx.x;
  const float* src; int C, roff, c0;
  if (bx < 64)      { src = q_w; C = 2048; roff = 0;    c0 = bx * 32; }
  else if (bx < 80) { src = k_w; C = 512;  roff = 2048; c0 = (bx - 64) * 32; }
  else              { src = v_w; C = 512;  roff = 2560; c0 = (bx - 80) * 32; }
  __shared__ float t[32][33];
  int r0 = blockIdx.y * 32;
  int row = threadIdx.x >> 3, c4 = (threadIdx.x & 7) * 4;
  float4 v = *(const float4*)(src + (size_t)(r0 + row) * C + c0 + c4);
  t[row][c4 + 0] = v.x; t[row][c4 + 1] = v.y; t[row][c4 + 2] = v.z; t[row][c4 + 3] = v.w;
  __syncthreads();
  ushortx4 oh, ol;
  #pragma unroll
  for (int i = 0; i < 4; ++i) {
    unsigned short hi, lo;
    split2(t[c4 + i][row], hi, lo);
    oh[i] = hi; ol[i] = lo;
  }
  size_t didx = (size_t)(roff + c0 + row) * 2048 + r0 + c4;
  *(ushortx4*)(dhi + didx) = oh;
  *(ushortx4*)(dlo + didx) = ol;
}

// ---------------- RMSNorm. MODE 0: -> hi/lo bf16. MODE 1: -> fp32 + hi bf16 ----------------
template<int MODE>
__global__ __launch_bounds__(256) void rms_kernel(const float* __restrict__ in,
                                                  const float* __restrict__ sc,
                                                  float* __restrict__ outf,
                                                  unsigned short* __restrict__ o1,
                                                  unsigned short* __restrict__ o2) {
  __shared__ float red[4];
  int row = blockIdx.x, tid = threadIdx.x;
  const float4* x4 = (const float4*)(in + (size_t)row * D_);
  float4 a = x4[tid], b = x4[tid + 256];
  float ss = a.x*a.x + a.y*a.y + a.z*a.z + a.w*a.w
           + b.x*b.x + b.y*b.y + b.z*b.z + b.w*b.w;
  #pragma unroll
  for (int off = 1; off < 64; off <<= 1) ss += __shfl_xor(ss, off);
  if ((tid & 63) == 0) red[tid >> 6] = ss;
  __syncthreads();
  float r = rsqrtf((red[0] + red[1] + red[2] + red[3]) * (1.0f / D_) + 1e-6f);
  const float4* s4 = (const float4*)sc;
  float4 sa = s4[tid], sb = s4[tid + 256];
  float va[8] = { a.x*r*sa.x, a.y*r*sa.y, a.z*r*sa.z, a.w*r*sa.w,
                  b.x*r*sb.x, b.y*r*sb.y, b.z*r*sb.z, b.w*r*sb.w };
  if (MODE == 0) {
    ushortx4 h0, l0, h1, l1;
    #pragma unroll
    for (int i = 0; i < 4; ++i) { unsigned short h, l; split2(va[i], h, l); h0[i] = h; l0[i] = l; }
    #pragma unroll
    for (int i = 0; i < 4; ++i) { unsigned short h, l; split2(va[4 + i], h, l); h1[i] = h; l1[i] = l; }
    *(ushortx4*)(o1 + (size_t)row * D_ + tid * 4) = h0;
    *(ushortx4*)(o2 + (size_t)row * D_ + tid * 4) = l0;
    *(ushortx4*)(o1 + (size_t)row * D_ + 1024 + tid * 4) = h1;
    *(ushortx4*)(o2 + (size_t)row * D_ + 1024 + tid * 4) = l1;
  } else {
    *(float4*)(outf + (size_t)row * D_ + tid * 4) = make_float4(va[0], va[1], va[2], va[3]);
    *(float4*)(outf + (size_t)row * D_ + 1024 + tid * 4) = make_float4(va[4], va[5], va[6], va[7]);
    ushortx4 h0 = { f2bf(va[0]), f2bf(va[1]), f2bf(va[2]), f2bf(va[3]) };
    ushortx4 h1 = { f2bf(va[4]), f2bf(va[5]), f2bf(va[6]), f2bf(va[7]) };
    *(ushortx4*)(o1 + (size_t)row * D_ + tid * 4) = h0;
    *(ushortx4*)(o1 + (size_t)row * D_ + 1024 + tid * 4) = h1;
  }
}

// ---------------- split GEMM 128-tile, gload_lds + XOR swizzle + 2-phase dbuf ----------------
template<int EPI>
__global__ __launch_bounds__(256) void gemm_bb128g(const unsigned short* __restrict__ Ahi,
                                                   const unsigned short* __restrict__ Alo,
                                                   const unsigned short* __restrict__ Bhi,
                                                   const unsigned short* __restrict__ Blo,
                                                   const float* __restrict__ res,
                                                   float* __restrict__ out,
                                                   int M, int Nn, int K) {
  int g = blockIdx.x;
  int nwg = gridDim.x;
  int per = nwg >> 3;
  int sw = (g & 7) * per + (g >> 3);
  int my = M >> 7;
  int xt = sw / my, yt = sw - xt * my;
  int m0 = yt * 128, n0 = xt * 128;
  __shared__ unsigned short Ah[2][128 * 32], Al[2][128 * 32];
  __shared__ unsigned short Bh[2][128 * 32], Bl[2][128 * 32];
  int tid = threadIdx.x, l = tid & 63, wid = tid >> 6;
  int lr = l & 15, lk = (l >> 4) * 8;
  int wr = (wid >> 1) * 64, wc = (wid & 1) * 64;
  int srl = l >> 2;
  int sch = ((l & 3) ^ (srl & 3)) * 8;
  size_t aoffs[2], boffs[2];
  int ldo[2];
  #pragma unroll
  for (int i = 0; i < 2; ++i) {
    int r = wid * 32 + i * 16 + srl;
    aoffs[i] = (size_t)(m0 + r) * K + sch;
    boffs[i] = (size_t)(n0 + r) * K + sch;
    ldo[i] = (wid * 32 + i * 16) * 32;
  }
  floatx4 acc[4][4];
  #pragma unroll
  for (int i = 0; i < 4; ++i)
    #pragma unroll
    for (int j = 0; j < 4; ++j) acc[i][j] = (floatx4){0.f, 0.f, 0.f, 0.f};

  auto stage = [&](int sel, int k0) {
    #pragma unroll
    for (int i = 0; i < 2; ++i) {
      gload16(Ahi + aoffs[i] + k0, &Ah[sel][ldo[i]]);
      gload16(Alo + aoffs[i] + k0, &Al[sel][ldo[i]]);
      gload16(Bhi + boffs[i] + k0, &Bh[sel][ldo[i]]);
      gload16(Blo + boffs[i] + k0, &Bl[sel][ldo[i]]);
    }
  };

  int rsw = ((l >> 4) ^ (lr & 3)) << 3;
  stage(0, 0);
  asm volatile("s_waitcnt vmcnt(0)" ::: "memory");
  __syncthreads();
  for (int k0 = 0; k0 < K; k0 += 32) {
    int cur = (k0 >> 5) & 1;
    if (k0 + 32 < K) stage(cur ^ 1, k0 + 32);
    short8 ah[4], al_[4];
    #pragma unroll
    for (int i = 0; i < 4; ++i) {
      int ao = (wr + i * 16 + lr) * 32 + rsw;
      ah[i]  = *(const short8*)&Ah[cur][ao];
      al_[i] = *(const short8*)&Al[cur][ao];
    }
    #pragma unroll
    for (int j = 0; j < 4; ++j) {
      int bo = (wc + j * 16 + lr) * 32 + rsw;
      short8 bh  = *(const short8*)&Bh[cur][bo];
      short8 bl_ = *(const short8*)&Bl[cur][bo];
      #pragma unroll
      for (int i = 0; i < 4; ++i) {
        acc[i][j] = __builtin_amdgcn_mfma_f32_16x16x32_bf16(ah[i], bh, acc[i][j], 0, 0, 0);
        acc[i][j] = __builtin_amdgcn_mfma_f32_16x16x32_bf16(ah[i], bl_, acc[i][j], 0, 0, 0);
        acc[i][j] = __builtin_amdgcn_mfma_f32_16x16x32_bf16(al_[i], bh, acc[i][j], 0, 0, 0);
      }
    }
    asm volatile("s_waitcnt vmcnt(0)" ::: "memory");
    __syncthreads();
  }
  int rq = (l >> 4) * 4;
  #pragma unroll
  for (int i = 0; i < 4; ++i)
    #pragma unroll
    for (int j = 0; j < 4; ++j)
      #pragma unroll
      for (int r = 0; r < 4; ++r) {
        size_t idx = (size_t)(m0 + wr + i * 16 + rq + r) * Nn + (n0 + wc + j * 16 + lr);
        float v = acc[i][j][r];
        if (EPI == 1) v += res[idx];
        out[idx] = v;
      }
}

// ---------------- per-head RMSNorm + RoPE -> split bf16 q/k ----------------
// qkvb: [NT][3072] fp32 packed (q at h*128, k at 2048+kvh*128, v at 2560+kvh*128)
__global__ __launch_bounds__(256) void qknorm_rope_kernel(const float* __restrict__ qkvb,
                                                          const float* __restrict__ qs,
                                                          const float* __restrict__ ks,
                                                          unsigned short* __restrict__ qhi,
                                                          unsigned short* __restrict__ qlo,
                                                          unsigned short* __restrict__ khi,
                                                          unsigned short* __restrict__ klo) {
  int gw = blockIdx.x * 4 + (threadIdx.x >> 6);
  int l = threadIdx.x & 63;
  const float* ptr; const float* sc; unsigned short *dhi, *dlo; int t;
  size_t orow;
  if (gw < NT_ * H_) {
    t = gw >> 4;
    ptr = qkvb + (size_t)t * 3072 + (gw & 15) * HD_;
    sc = qs; dhi = qhi; dlo = qlo; orow = (size_t)gw * HD_;
  } else {
    int r = gw - NT_ * H_;
    t = r >> 2;
    ptr = qkvb + (size_t)t * 3072 + 2048 + (r & 3) * HD_;
    sc = ks; dhi = khi; dlo = klo; orow = (size_t)r * HD_;
  }
  int pos = t & (SS_ - 1);
  float2 x = *(const float2*)(ptr + 2 * l);
  float p2 = x.x * x.x + x.y * x.y;
  #pragma unroll
  for (int off = 1; off < 64; off <<= 1) p2 += __shfl_xor(p2, off);
  float rms = rsqrtf(p2 * (1.0f / HD_) + 1e-6f);
  float nx = x.x * rms * sc[2 * l];
  float ny = x.y * rms * sc[2 * l + 1];
  int j0 = (2 * l) & 63;
  float ang0 = pos * __expf(-(float)j0 * (13.815510557964274f / 64.0f));
  float ang1 = pos * __expf(-(float)(j0 + 1) * (13.815510557964274f / 64.0f));
  float s0, c0, s1, c1;
  sincosf(ang0, &s0, &c0);
  sincosf(ang1, &s1, &c1);
  float ox = __shfl_xor(nx, 32);
  float oy = __shfl_xor(ny, 32);
  float r0, r1;
  if (l < 32) { r0 = nx * c0 - ox * s0; r1 = ny * c1 - oy * s1; }
  else        { r0 = nx * c0 + ox * s0; r1 = ny * c1 + oy * s1; }
  unsigned short h0, l0, h1, l1;
  split2(r0, h0, l0);
  split2(r1, h1, l1);
  *(unsigned*)(dhi + orow + 2 * l) = (unsigned)h0 | ((unsigned)h1 << 16);
  *(unsigned*)(dlo + orow + 2 * l) = (unsigned)l0 | ((unsigned)l1 << 16);
}

// ---------------- V split + transpose: packed qkvb [NT][3072] -> hi/lo bf16 [b kvh d s] ------
__global__ __launch_bounds__(256) void vsplit_kernel(const float* __restrict__ qkvb,
                                                     unsigned short* __restrict__ vthi,
                                                     unsigned short* __restrict__ vtlo) {
  int d0 = blockIdx.x * 32, s0 = blockIdx.y * 32, bk = blockIdx.z;
  int b = bk >> 2, kvh = bk & 3;
  __shared__ float t[32][33];
  int row = threadIdx.x >> 3, c4 = (threadIdx.x & 7) * 4;
  float4 v = *(const float4*)(qkvb + (size_t)(b * SS_ + s0 + row) * 3072 + 2560 + kvh * HD_ + d0 + c4);
  t[row][c4 + 0] = v.x; t[row][c4 + 1] = v.y; t[row][c4 + 2] = v.z; t[row][c4 + 3] = v.w;
  __syncthreads();
  ushortx4 oh, ol;
  #pragma unroll
  for (int i = 0; i < 4; ++i) {
    unsigned short hi, lo;
    split2(t[c4 + i][row], hi, lo);
    oh[i] = hi; ol[i] = lo;
  }
  size_t idx = ((size_t)(b * KVH_ + kvh) * HD_ + d0 + row) * SS_ + s0 + c4;
  *(ushortx4*)(vthi + idx) = oh;
  *(ushortx4*)(vtlo + idx) = ol;
}

// ---------------- MFMA flash attention: LDS-staged KV, 2-phase dbuf prefetch ----------------
// Co-resident block pairs differ by blockIdx.z (stride-256 round-robin), so batch 1 runs the
// reversed qt order: per-CU causal work = (2x+2)+(2(15-x)+2) = 34 tiles, uniform.
__global__ __launch_bounds__(256) void attn_kernel(const unsigned short* __restrict__ qhi,
                                                   const unsigned short* __restrict__ qlo,
                                                   const unsigned short* __restrict__ khi,
                                                   const unsigned short* __restrict__ klo,
                                                   const unsigned short* __restrict__ vthi,
                                                   const unsigned short* __restrict__ vtlo,
                                                   unsigned short* __restrict__ ctx_hi,
                                                   unsigned short* __restrict__ ctx_lo) {
  int qtx = blockIdx.x, h = blockIdx.y, b = blockIdx.z;
  int qt = (b & 1) ? ((int)gridDim.x - 1 - qtx) : qtx;
  int kvh = h >> 2;
  int tid = threadIdx.x, l = tid & 63, wid = tid >> 6;
  int lr = l & 15, lk = (l >> 4) * 8;
  __shared__ unsigned short Kh[2][32 * 128], Kl[2][32 * 128];
  __shared__ unsigned short Vh[2][128 * 32], Vl[2][128 * 32];
  __shared__ unsigned short Ph[64 * 40], Pl[64 * 40];
  int qt0 = qt * 64;

  size_t qrow = ((size_t)((b * SS_ + qt0 + wid * 16 + lr) * H_) + h) * HD_;
  short8 qfh[4], qfl[4];
  #pragma unroll
  for (int t = 0; t < 4; ++t) {
    qfh[t] = *(const short8*)(qhi + qrow + t * 32 + lk);
    qfl[t] = *(const short8*)(qlo + qrow + t * 32 + lk);
  }

  float m[4], sum[4];
  #pragma unroll
  for (int r = 0; r < 4; ++r) { m[r] = -__builtin_inff(); sum[r] = 0.f; }
  floatx4 o[8];
  #pragma unroll
  for (int cb = 0; cb < 8; ++cb) o[cb] = (floatx4){0.f, 0.f, 0.f, 0.f};

  size_t vbase = ((size_t)(b * KVH_ + kvh) * HD_) * SS_;
  int nt = 2 * qt + 2;

  auto stage = [&](int sel, int kt) {
    int k0 = kt * 32;
    #pragma unroll
    for (int i = 0; i < 2; ++i) {
      int r = wid * 8 + i * 4 + (l >> 4);
      int ch = (l & 15) ^ (r & 7);
      size_t gk = ((size_t)((b * SS_ + k0 + r) * KVH_) + kvh) * HD_ + ch * 8;
      gload16(khi + gk, &Kh[sel][(wid * 8 + i * 4) * 128]);
      gload16(klo + gk, &Kl[sel][(wid * 8 + i * 4) * 128]);
    }
    #pragma unroll
    for (int i = 0; i < 2; ++i) {
      int r = wid * 32 + i * 16 + (l >> 2);
      int ch = (l & 3) ^ (r & 3);
      size_t gv = vbase + (size_t)r * SS_ + k0 + ch * 8;
      gload16(vthi + gv, &Vh[sel][(wid * 32 + i * 16) * 32]);
      gload16(vtlo + gv, &Vl[sel][(wid * 32 + i * 16) * 32]);
    }
  };

  stage(0, 0);
  asm volatile("s_waitcnt vmcnt(0)" ::: "memory");
  __syncthreads();

  for (int kt = 0; kt < nt; ++kt) {
    int cur = kt & 1;
    if (kt + 1 < nt) stage(cur ^ 1, kt + 1);
    int k0 = kt * 32;
    float sv[2][4];
    #pragma unroll
    for (int kbk = 0; kbk < 2; ++kbk) {
      int kr = kbk * 16 + lr;
      floatx4 s = (floatx4){0.f, 0.f, 0.f, 0.f};
      #pragma unroll
      for (int t = 0; t < 4; ++t) {
        int co = kr * 128 + (((t * 4 + (l >> 4)) ^ (lr & 7)) << 3);
        short8 kfh = *(const short8*)&Kh[cur][co];
        short8 kfl = *(const short8*)&Kl[cur][co];
        s = __builtin_amdgcn_mfma_f32_16x16x32_bf16(qfh[t], kfh, s, 0, 0, 0);
        s = __builtin_amdgcn_mfma_f32_16x16x32_bf16(qfh[t], kfl, s, 0, 0, 0);
        s = __builtin_amdgcn_mfma_f32_16x16x32_bf16(qfl[t], kfh, s, 0, 0, 0);
      }
      int key = k0 + kr;
      #pragma unroll
      for (int r = 0; r < 4; ++r) {
        int q = qt0 + wid * 16 + (l >> 4) * 4 + r;
        float x = s[r] * 0.08838834764831845f;
        sv[kbk][r] = (key <= q) ? x : -1e30f;
      }
    }
    float f[4], p[2][4];
    #pragma unroll
    for (int r = 0; r < 4; ++r) {
      float tm = fmaxf(sv[0][r], sv[1][r]);
      tm = fmaxf(tm, __shfl_xor(tm, 1));
      tm = fmaxf(tm, __shfl_xor(tm, 2));
      tm = fmaxf(tm, __shfl_xor(tm, 4));
      tm = fmaxf(tm, __shfl_xor(tm, 8));
      float mn = fmaxf(m[r], tm);
      f[r] = __expf(m[r] - mn);
      m[r] = mn;
      float rs = 0.f;
      #pragma unroll
      for (int kbk = 0; kbk < 2; ++kbk) { p[kbk][r] = __expf(sv[kbk][r] - mn); rs += p[kbk][r]; }
      rs += __shfl_xor(rs, 1); rs += __shfl_xor(rs, 2);
      rs += __shfl_xor(rs, 4); rs += __shfl_xor(rs, 8);
      sum[r] = sum[r] * f[r] + rs;
    }
    #pragma unroll
    for (int kbk = 0; kbk < 2; ++kbk)
      #pragma unroll
      for (int r = 0; r < 4; ++r)
        split2(p[kbk][r],
               Ph[(wid * 16 + (l >> 4) * 4 + r) * 40 + kbk * 16 + lr],
               Pl[(wid * 16 + (l >> 4) * 4 + r) * 40 + kbk * 16 + lr]);
    #pragma unroll
    for (int cb = 0; cb < 8; ++cb)
      #pragma unroll
      for (int r = 0; r < 4; ++r) o[cb][r] = o[cb][r] * f[r];
    int pco = (wid * 16 + lr) * 40 + lk;
    short8 pah = *(const short8*)&Ph[pco];
    short8 pal = *(const short8*)&Pl[pco];
    #pragma unroll
    for (int cb = 0; cb < 8; ++cb) {
      int vo = (cb * 16 + lr) * 32 + (((l >> 4) ^ (lr & 3)) << 3);
      short8 vbh = *(const short8*)&Vh[cur][vo];
      short8 vbl = *(const short8*)&Vl[cur][vo];
      o[cb] = __builtin_amdgcn_mfma_f32_16x16x32_bf16(pah, vbh, o[cb], 0, 0, 0);
      o[cb] = __builtin_amdgcn_mfma_f32_16x16x32_bf16(pah, vbl, o[cb], 0, 0, 0);
      o[cb] = __builtin_amdgcn_mfma_f32_16x16x32_bf16(pal, vbh, o[cb], 0, 0, 0);
    }
    asm volatile("s_waitcnt vmcnt(0)" ::: "memory");
    __syncthreads();
  }
  #pragma unroll
  for (int cb = 0; cb < 8; ++cb)
    #pragma unroll
    for (int r = 0; r < 4; ++r) {
      int q = qt0 + wid * 16 + (l >> 4) * 4 + r;
      int d = cb * 16 + lr;
      float val = o[cb][r] / sum[r];
      unsigned short hi, lo;
      split2(val, hi, lo);
      size_t idx = ((size_t)(b * SS_ + q)) * (H_ * HD_) + h * HD_ + d;
      ctx_hi[idx] = hi;
      ctx_lo[idx] = lo;
    }
}

// ---------------- Router (fp32) ----------------
__global__ __launch_bounds__(256) void router_kernel(const float* __restrict__ x2,
                                                     const float* __restrict__ gw,
                                                     float* __restrict__ logits) {
  int t = blockIdx.x * 4 + (threadIdx.x >> 6);
  int l = threadIdx.x & 63;
  float acc[32];
  #pragma unroll
  for (int e = 0; e < 32; ++e) acc[e] = 0.f;
  for (int i = 0; i < 32; ++i) {
    int d = i * 64 + l;
    float xv = x2[(size_t)t * D_ + d];
    const float4* wr = (const float4*)(gw + (size_t)d * E_);
    #pragma unroll
    for (int j = 0; j < 8; ++j) {
      float4 wv = wr[j];
      acc[4 * j + 0] += xv * wv.x; acc[4 * j + 1] += xv * wv.y;
      acc[4 * j + 2] += xv * wv.z; acc[4 * j + 3] += xv * wv.w;
    }
  }
  #pragma unroll
  for (int e = 0; e < 32; ++e) {
    acc[e] += __shfl_xor(acc[e], 1);  acc[e] += __shfl_xor(acc[e], 2);
    acc[e] += __shfl_xor(acc[e], 4);  acc[e] += __shfl_xor(acc[e], 8);
    acc[e] += __shfl_xor(acc[e], 16); acc[e] += __shfl_xor(acc[e], 32);
  }
  if (l == 0) {
    #pragma unroll
    for (int e = 0; e < 32; ++e) logits[(size_t)t * E_ + e] = acc[e];
  }
}

// -------- fused routing: top-8 + softmax + count + scan + scatter, single block --------
__global__ __launch_bounds__(256) void route_kernel(const float* __restrict__ logits,
                                                    int* __restrict__ sel, float* __restrict__ wts,
                                                    int* __restrict__ counts, int* __restrict__ offs,
                                                    int* __restrict__ pair_t, float* __restrict__ pair_w,
                                                    int* __restrict__ pos) {
  __shared__ int cnt[E_];
  __shared__ int curs[E_];
  int tid = threadIdx.x;
  if (tid < E_) cnt[tid] = 0;
  __syncthreads();
  for (int kb = 0; kb < NT_ / 256; ++kb) {
    int t = kb * 256 + tid;
    float v[32];
    #pragma unroll
    for (int e = 0; e < 32; ++e) v[e] = logits[(size_t)t * E_ + e];
    float val[8]; int idx[8];
    for (int k = 0; k < 8; ++k) {
      float best = -__builtin_inff(); int bi = 0;
      for (int e = 0; e < 32; ++e) if (v[e] > best) { best = v[e]; bi = e; }
      val[k] = best; idx[k] = bi; v[bi] = -__builtin_inff();
    }
    float mx = val[0], s = 0.f; float ex[8];
    for (int k = 0; k < 8; ++k) { ex[k] = expf(val[k] - mx); s += ex[k]; }
    float inv = 1.f / s;
    for (int k = 0; k < 8; ++k) {
      sel[t * 8 + k] = idx[k];
      wts[t * 8 + k] = ex[k] * inv;
      atomicAdd(&cnt[idx[k]], 1);
    }
  }
  __syncthreads();
  if (tid == 0) {
    int c = 0;
    for (int e = 0; e < E_; ++e) {
      offs[e] = c; curs[e] = c; counts[e] = cnt[e]; c += cnt[e];
    }
  }
  __syncthreads();
  for (int g = tid; g < NPAIR_; g += 256) {
    int e = sel[g];
    int p = atomicAdd(&curs[e], 1);
    pair_t[p] = g >> 3;
    pair_w[p] = wts[g];
    pos[g] = p;
  }
}

// ---------------- gate+up expert GEMM: 4-wave 128x(64G+64U), BK=32, 3-stage counted vmcnt ----
__global__ __launch_bounds__(256, 3) void gateup_kernel(const unsigned short* __restrict__ xbf,
                                                        const unsigned short* __restrict__ gT,
                                                        const unsigned short* __restrict__ uT,
                                                        const int* __restrict__ counts,
                                                        const int* __restrict__ offs,
                                                        const int* __restrict__ pair_t,
                                                        const float* __restrict__ pair_w,
                                                        unsigned short* __restrict__ act) {
  int g = blockIdx.x;
  int lg = (g & ~127) | (((g & 7) << 4) | ((g >> 3) & 15));
  int e = lg / 192;                       // 12 xt * 16 yt per expert
  int rem = lg - e * 192;
  int xt = rem >> 4, yt = rem & 15;
  int cnt = counts[e];
  int r0 = yt * 128;
  if (r0 >= cnt) return;
  int base = offs[e];
  int n0 = xt * 64;
  const unsigned short* G = gT + (size_t)e * F_ * D_;
  const unsigned short* U = uT + (size_t)e * F_ * D_;
  __shared__ unsigned short As[3][128 * 32], Gs[3][64 * 32], Us[3][64 * 32];   // 48 KB
  int tid = threadIdx.x, l = tid & 63, wid = tid >> 6;   // 4 waves
  int lr = l & 15, lk16 = l >> 4;
  int srl = l >> 2;                            // staging row-in-16
  int sch = ((l & 3) ^ ((srl >> 1) & 3)) * 8;  // conflict-free XOR (matches read side)
  const unsigned short* asrc[2];
  #pragma unroll
  for (int i = 0; i < 2; ++i) {
    int rowt = wid * 32 + i * 16 + srl;
    int cr = r0 + rowt; if (cr > cnt - 1) cr = cnt - 1;
    asrc[i] = xbf + (size_t)pair_t[base + cr] * D_ + sch;
  }
  const unsigned short* gsrc = G + (size_t)(n0 + wid * 16 + srl) * D_ + sch;
  const unsigned short* usrc = U + (size_t)(n0 + wid * 16 + srl) * D_ + sch;
  int wm = wid >> 1;    // 0..1 -> 64 rows
  int wn = wid & 1;     // 0..1 -> 32 cols of G and U
  floatx4 ag[4][2], au[4][2];
  #pragma unroll
  for (int i = 0; i < 4; ++i)
    #pragma unroll
    for (int j = 0; j < 2; ++j) { ag[i][j] = (floatx4){0.f,0.f,0.f,0.f}; au[i][j] = (floatx4){0.f,0.f,0.f,0.f}; }

  auto stage = [&](int sel, int kofs) {    // 4 loads per lane
    gload16(asrc[0] + kofs, &As[sel][(wid * 32) * 32]);
    gload16(asrc[1] + kofs, &As[sel][(wid * 32 + 16) * 32]);
    gload16(gsrc + kofs, &Gs[sel][(wid * 16) * 32]);
    gload16(usrc + kofs, &Us[sel][(wid * 16) * 32]);
  };

  const int nt = D_ / 32;   // 64
  stage(0, 0);
  stage(1, 32);
  for (int t = 0; t < nt; ++t) {
    int cur = t % 3;
    if (t + 1 < nt) { asm volatile("s_waitcnt vmcnt(4)" ::: "memory"); }
    else            { asm volatile("s_waitcnt vmcnt(0)" ::: "memory"); }
    __builtin_amdgcn_sched_barrier(0);
    __syncthreads();                      // all waves past iter t-1 reads of buf (t+2)%3
    if (t + 2 < nt) stage((t + 2) % 3, (t + 2) * 32);
    int co = (lk16 ^ ((lr >> 1) & 3)) << 3;
    short8 a[4], gg[2], uu[2];
    #pragma unroll
    for (int i = 0; i < 4; ++i)
      a[i] = *(const short8*)&As[cur][(wm * 64 + i * 16 + lr) * 32 + co];
    #pragma unroll
    for (int j = 0; j < 2; ++j) {
      gg[j] = *(const short8*)&Gs[cur][(wn * 32 + j * 16 + lr) * 32 + co];
      uu[j] = *(const short8*)&Us[cur][(wn * 32 + j * 16 + lr) * 32 + co];
    }
    __builtin_amdgcn_s_setprio(1);
    #pragma unroll
    for (int i = 0; i < 4; ++i)
      #pragma unroll
      for (int j = 0; j < 2; ++j) {
        ag[i][j] = __builtin_amdgcn_mfma_f32_16x16x32_bf16(a[i], gg[j], ag[i][j], 0, 0, 0);
        au[i][j] = __builtin_amdgcn_mfma_f32_16x16x32_bf16(a[i], uu[j], au[i][j], 0, 0, 0);
      }
    __builtin_amdgcn_s_setprio(0);
  }
  int rq = (l >> 4) * 4;
  #pragma unroll
  for (int i = 0; i < 4; ++i)
    #pragma unroll
    for (int r = 0; r < 4; ++r) {
      int rowl = wm * 64 + i * 16 + rq + r;
      if (r0 + rowl < cnt) {
        int p = base + r0 + rowl;
        float pw = pair_w[p];
        size_t orow = (size_t)p * F_;
        #pragma unroll
        for (int j = 0; j < 2; ++j) {
          float gv = ag[i][j][r], uv = au[i][j][r];
          float a = (gv / (1.f + __expf(-gv))) * uv * pw;
          act[orow + n0 + wn * 32 + j * 16 + lr] = f2bf(a);
        }
      }
    }
}

// ---------------- down expert GEMM: 4-wave 128x128, BK=32, 3-stage counted vmcnt, bf16 out ----
__global__ __launch_bounds__(256, 3) void down_kernel(const unsigned short* __restrict__ act,
                                                      const unsigned short* __restrict__ dT,
                                                      const int* __restrict__ counts,
                                                      const int* __restrict__ offs,
                                                      unsigned short* __restrict__ dpre) {
  int g = blockIdx.x;
  int lg = (g & ~255) | (((g & 7) << 5) | ((g >> 3) & 31));
  int e = lg >> 8;                     // 16 xt * 16 yt per expert
  int rem = lg & 255;
  int xt = rem >> 4, yt = rem & 15;
  int cnt = counts[e];
  int r0 = yt * 128;
  if (r0 >= cnt) return;
  int base = offs[e];
  int n0 = xt * 128;
  const unsigned short* B = dT + (size_t)e * ((size_t)D_ * F_);
  __shared__ unsigned short As[3][128 * 32], Bs[3][128 * 32];   // 48 KB
  int tid = threadIdx.x, l = tid & 63, wid = tid >> 6;
  int lr = l & 15, lk16 = l >> 4;
  int srl = l >> 2;
  int sch = ((l & 3) ^ ((srl >> 1) & 3)) * 8;
  const unsigned short* asrc[2];
  const unsigned short* bsrc[2];
  #pragma unroll
  for (int i = 0; i < 2; ++i) {
    int rowt = wid * 32 + i * 16 + srl;
    int cr = r0 + rowt; if (cr > cnt - 1) cr = cnt - 1;
    asrc[i] = act + (size_t)(base + cr) * F_ + sch;
    bsrc[i] = B + (size_t)(n0 + rowt) * F_ + sch;
  }
  int wm = wid >> 1;    // 0..1 -> 64 rows
  int wn = wid & 1;     // 0..1 -> 64 cols
  floatx4 acc[4][4];
  #pragma unroll
  for (int i = 0; i < 4; ++i)
    #pragma unroll
    for (int j = 0; j < 4; ++j) acc[i][j] = (floatx4){0.f, 0.f, 0.f, 0.f};

  auto stage = [&](int sel, int kofs) {    // 4 loads per lane
    gload16(asrc[0] + kofs, &As[sel][(wid * 32) * 32]);
    gload16(asrc[1] + kofs, &As[sel][(wid * 32 + 16) * 32]);
    gload16(bsrc[0] + kofs, &Bs[sel][(wid * 32) * 32]);
    gload16(bsrc[1] + kofs, &Bs[sel][(wid * 32 + 16) * 32]);
  };

  const int nt = F_ / 32;   // 24
  stage(0, 0);
  stage(1, 32);
  for (int t = 0; t < nt; ++t) {
    int cur = t % 3;
    if (t + 1 < nt) { asm volatile("s_waitcnt vmcnt(4)" ::: "memory"); }
    else            { asm volatile("s_waitcnt vmcnt(0)" ::: "memory"); }
    __builtin_amdgcn_sched_barrier(0);
    __syncthreads();
    if (t + 2 < nt) stage((t + 2) % 3, (t + 2) * 32);
    int co = (lk16 ^ ((lr >> 1) & 3)) << 3;
    short8 a[4], b_[4];
    #pragma unroll
    for (int i = 0; i < 4; ++i) {
      a[i]  = *(const short8*)&As[cur][(wm * 64 + i * 16 + lr) * 32 + co];
      b_[i] = *(const short8*)&Bs[cur][(wn * 64 + i * 16 + lr) * 32 + co];
    }
    __builtin_amdgcn_s_setprio(1);
    #pragma unroll
    for (int i = 0; i < 4; ++i)
      #pragma unroll
      for (int j = 0; j < 4; ++j)
        acc[i][j] = __builtin_amdgcn_mfma_f32_16x16x32_bf16(a[i], b_[j], acc[i][j], 0, 0, 0);
    __builtin_amdgcn_s_setprio(0);
  }
  int rq = (l >> 4) * 4;
  #pragma unroll
  for (int i = 0; i < 4; ++i)
    #pragma unroll
    for (int r = 0; r < 4; ++r) {
      int rowl = wm * 64 + i * 16 + rq + r;
      if (r0 + rowl < cnt) {
        size_t orow = (size_t)(base + r0 + rowl) * D_;
        #pragma unroll
        for (int j = 0; j < 4; ++j)
          dpre[orow + n0 + wn * 64 + j * 16 + lr] = f2bf(acc[i][j][r]);
      }
    }
}

// ---------------- MoE gather: out[t] += sum_k dpre_bf16[pos[t*8+k]] ----------------
__global__ __launch_bounds__(256) void moe_gather_kernel(const unsigned short* __restrict__ dpre,
                                                         const int* __restrict__ pos,
                                                         float* __restrict__ out) {
  int t = blockIdx.x;
  int tid = threadIdx.x;
  int p[8];
  #pragma unroll
  for (int k = 0; k < 8; ++k) p[k] = pos[t * 8 + k];
  size_t orow = (size_t)t * D_;
  int col = tid * 8;
  float s[8];
  float4 o0 = *(const float4*)(out + orow + col);
  float4 o1 = *(const float4*)(out + orow + col + 4);
  s[0] = o0.x; s[1] = o0.y; s[2] = o0.z; s[3] = o0.w;
  s[4] = o1.x; s[5] = o1.y; s[6] = o1.z; s[7] = o1.w;
  #pragma unroll
  for (int k = 0; k < 8; ++k) {
    short8 v = *(const short8*)(dpre + (size_t)p[k] * D_ + col);
    #pragma unroll
    for (int j = 0; j < 8; ++j) s[j] += bf2f((unsigned short)v[j]);
  }
  *(float4*)(out + orow + col) = make_float4(s[0], s[1], s[2], s[3]);
  *(float4*)(out + orow + col + 4) = make_float4(s[4], s[5], s[6], s[7]);
}

// ---------------- launch ----------------
extern "C" void kernel_launch(void* const* d_in, const int* in_sizes, int n_in,
                              void* d_out, int out_size, void* d_ws, size_t ws_size,
                              hipStream_t stream) {
  const float* hidden  = (const float*)d_in[0];
  const float* in_ln   = (const float*)d_in[2];
  const float* post_ln = (const float*)d_in[3];
  const float* q_w     = (const float*)d_in[4];
  const float* k_w     = (const float*)d_in[5];
  const float* v_w     = (const float*)d_in[6];
  const float* o_w     = (const float*)d_in[7];
  const float* q_ns    = (const float*)d_in[8];
  const float* k_ns    = (const float*)d_in[9];
  const float* gate_w  = (const float*)d_in[10];
  const float* gate_p  = (const float*)d_in[11];
  const float* up_p    = (const float*)d_in[12];
  const float* down_p  = (const float*)d_in[13];
  float* out = (float*)d_out;

  char* w = (char*)d_ws;
  size_t off = 0;
  auto alloc = [&](size_t b) { char* p = w + off; off += (b + 255) & ~(size_t)255; return p; };
  unsigned short* qkvThi = (unsigned short*)alloc((size_t)3072 * 2048 * 2);
  unsigned short* qkvTlo = (unsigned short*)alloc((size_t)3072 * 2048 * 2);
  unsigned short* oThi = (unsigned short*)alloc((size_t)2048 * 2048 * 2);
  unsigned short* oTlo = (unsigned short*)alloc((size_t)2048 * 2048 * 2);
  unsigned short* gT   = (unsigned short*)alloc((size_t)E_ * F_ * D_ * 2);
  unsigned short* uT   = (unsigned short*)alloc((size_t)E_ * F_ * D_ * 2);
  unsigned short* dT   = (unsigned short*)alloc((size_t)E_ * D_ * F_ * 2);
  unsigned short* h_hi = (unsigned short*)alloc((size_t)NT_ * D_ * 2);
  unsigned short* h_lo = (unsigned short*)alloc((size_t)NT_ * D_ * 2);
  float* qkvbuf = (float*)alloc((size_t)NT_ * 3072 * 4);
  unsigned short* qhi = (unsigned short*)alloc((size_t)NT_ * H_ * HD_ * 2);
  unsigned short* qlo = (unsigned short*)alloc((size_t)NT_ * H_ * HD_ * 2);
  unsigned short* khi = (unsigned short*)alloc((size_t)NT_ * KVH_ * HD_ * 2);
  unsigned short* klo = (unsigned short*)alloc((size_t)NT_ * KVH_ * HD_ * 2);
  unsigned short* vthi = (unsigned short*)alloc((size_t)NT_ * KVH_ * HD_ * 2);
  unsigned short* vtlo = (unsigned short*)alloc((size_t)NT_ * KVH_ * HD_ * 2);
  unsigned short* ctx_hi = (unsigned short*)alloc((size_t)NT_ * H_ * HD_ * 2);
  unsigned short* ctx_lo = (unsigned short*)alloc((size_t)NT_ * H_ * HD_ * 2);
  float* x2    = (float*)alloc((size_t)NT_ * D_ * 4);
  unsigned short* x2bf = (unsigned short*)alloc((size_t)NT_ * D_ * 2);
  float* logits = (float*)alloc((size_t)NT_ * E_ * 4);
  int*   sel    = (int*)alloc((size_t)NT_ * TOPK_ * 4);
  float* wts    = (float*)alloc((size_t)NT_ * TOPK_ * 4);
  int*   counts = (int*)alloc(E_ * 4);
  int*   offs   = (int*)alloc(E_ * 4);
  int*   pair_t = (int*)alloc((size_t)NPAIR_ * 4);
  float* pair_w = (float*)alloc((size_t)NPAIR_ * 4);
  int*   pos    = (int*)alloc((size_t)NPAIR_ * 4);
  unsigned short* act = (unsigned short*)alloc((size_t)NPAIR_ * F_ * 2);
  unsigned short* dpre = (unsigned short*)alloc((size_t)NPAIR_ * D_ * 2);

  // weight prep (Q, K, V transposed-split into one packed [3072][2048] matrix, single launch)
  tsplit_qkv_kernel<<<dim3(96, 64), 256, 0, stream>>>(q_w, k_w, v_w, qkvThi, qkvTlo);
  tsplit_kernel<<<dim3(64, 64), 256, 0, stream>>>(o_w, oThi, oTlo, 2048, 2048);
  tconv_gu_kernel<<<dim3(24, 64, 64), 256, 0, stream>>>(gate_p, up_p, gT, uT);
  tconv_kernel<<<dim3(64, 24, 32), 256, 0, stream>>>(down_p, dT, 768, 2048);

  rms_kernel<0><<<NT_, 256, 0, stream>>>(hidden, in_ln, nullptr, h_hi, h_lo);
  gemm_bb128g<0><<<384, 256, 0, stream>>>(h_hi, h_lo, qkvThi, qkvTlo, nullptr, qkvbuf, NT_, 3072, 2048);
  qknorm_rope_kernel<<<(NT_ * (H_ + KVH_)) / 4, 256, 0, stream>>>(qkvbuf, q_ns, k_ns,
                                                                  qhi, qlo, khi, klo);
  vsplit_kernel<<<dim3(HD_ / 32, SS_ / 32, NB_ * KVH_), 256, 0, stream>>>(qkvbuf, vthi, vtlo);
  attn_kernel<<<dim3(SS_ / 64, H_, NB_), 256, 0, stream>>>(qhi, qlo, khi, klo, vthi, vtlo,
                                                           ctx_hi, ctx_lo);
  gemm_bb128g<1><<<256, 256, 0, stream>>>(ctx_hi, ctx_lo, oThi, oTlo, hidden, out, NT_, 2048, 2048);
  rms_kernel<1><<<NT_, 256, 0, stream>>>(out, post_ln, x2, x2bf, nullptr);
  router_kernel<<<NT_ / 4, 256, 0, stream>>>(x2, gate_w, logits);
  route_kernel<<<1, 256, 0, stream>>>(logits, sel, wts, counts, offs, pair_t, pair_w, pos);
  gateup_kernel<<<192 * 32, 256, 0, stream>>>(x2bf, gT, uT, counts, offs, pair_t, pair_w, act);
  down_kernel<<<256 * 32, 256, 0, stream>>>(act, dT, counts, offs, dpre);
  moe_gather_kernel<<<NT_, 256, 0, stream>>>(dpre, pos, out);
}

// Round 23
// 929.273 us; speedup vs baseline: 1.0326x; 1.0326x over previous
//
#include <hip/hip_runtime.h>
#include <hip/hip_bf16.h>

#define D_ 2048
#define H_ 16
#define KVH_ 4
#define HD_ 128
#define E_ 32
#define TOPK_ 8
#define F_ 768
#define NB_ 2
#define SS_ 1024
#define NT_ 2048
#define NPAIR_ 16384

typedef __attribute__((ext_vector_type(8))) short short8;
typedef __attribute__((ext_vector_type(4))) float floatx4;
typedef __attribute__((ext_vector_type(4))) unsigned int uintx4;
typedef __attribute__((ext_vector_type(4))) unsigned short ushortx4;

__device__ __forceinline__ unsigned short f2bf(float f) {
  union { float f; unsigned u; } v; v.f = f;
  unsigned r = v.u + 0x7FFFu + ((v.u >> 16) & 1u);
  return (unsigned short)(r >> 16);
}
__device__ __forceinline__ float bf2f(unsigned short h) {
  union { unsigned u; float f; } v; v.u = ((unsigned)h) << 16;
  return v.f;
}
__device__ __forceinline__ void split2(float v, unsigned short& hi, unsigned short& lo) {
  unsigned short h = f2bf(v);
  hi = h;
  lo = f2bf(v - bf2f(h));
}
// async global->LDS, 16B per lane; LDS dest = wave-uniform base + lane*16
__device__ __forceinline__ void gload16(const unsigned short* g, unsigned short* l) {
  __builtin_amdgcn_global_load_lds(
      (const __attribute__((address_space(1))) unsigned int*)g,
      (__attribute__((address_space(3))) unsigned int*)l, 16, 0, 0);
}

// ---------------- weight transpose + convert: fp32 [R][C] -> bf16 [C][R] ----------------
__global__ __launch_bounds__(256) void tconv_kernel(const float* __restrict__ src,
                                                    unsigned short* __restrict__ dst,
                                                    int R, int C) {
  size_t off = (size_t)blockIdx.z * R * C;
  src += off; dst += off;
  __shared__ float t[32][33];
  int c0 = blockIdx.x * 32, r0 = blockIdx.y * 32;
  int row = threadIdx.x >> 3, c4 = (threadIdx.x & 7) * 4;
  float4 v = *(const float4*)(src + (size_t)(r0 + row) * C + c0 + c4);
  t[row][c4 + 0] = v.x; t[row][c4 + 1] = v.y; t[row][c4 + 2] = v.z; t[row][c4 + 3] = v.w;
  __syncthreads();
  ushortx4 o = { f2bf(t[c4 + 0][row]), f2bf(t[c4 + 1][row]),
                 f2bf(t[c4 + 2][row]), f2bf(t[c4 + 3][row]) };
  *(ushortx4*)(dst + (size_t)(c0 + row) * R + r0 + c4) = o;
}

// ---------------- fused gate+up transpose+convert: z<32 -> gate expert z, else up expert z-32 --
__global__ __launch_bounds__(256) void tconv_gu_kernel(const float* __restrict__ gp,
                                                       const float* __restrict__ up,
                                                       unsigned short* __restrict__ gT,
                                                       unsigned short* __restrict__ uT) {
  int z = blockIdx.z;
  const float* src;
  unsigned short* dst;
  if (z < 32) { src = gp + (size_t)z * 2048 * 768; dst = gT + (size_t)z * 2048 * 768; }
  else        { src = up + (size_t)(z - 32) * 2048 * 768; dst = uT + (size_t)(z - 32) * 2048 * 768; }
  __shared__ float t[32][33];
  int c0 = blockIdx.x * 32, r0 = blockIdx.y * 32;
  int row = threadIdx.x >> 3, c4 = (threadIdx.x & 7) * 4;
  float4 v = *(const float4*)(src + (size_t)(r0 + row) * 768 + c0 + c4);
  t[row][c4 + 0] = v.x; t[row][c4 + 1] = v.y; t[row][c4 + 2] = v.z; t[row][c4 + 3] = v.w;
  __syncthreads();
  ushortx4 o = { f2bf(t[c4 + 0][row]), f2bf(t[c4 + 1][row]),
                 f2bf(t[c4 + 2][row]), f2bf(t[c4 + 3][row]) };
  *(ushortx4*)(dst + (size_t)(c0 + row) * 2048 + r0 + c4) = o;
}

// ---------------- weight transpose + split: fp32 [R][C] -> hi/lo bf16 [C][R] ----------------
__global__ __launch_bounds__(256) void tsplit_kernel(const float* __restrict__ src,
                                                     unsigned short* __restrict__ dhi,
                                                     unsigned short* __restrict__ dlo,
                                                     int R, int C) {
  __shared__ float t[32][33];
  int c0 = blockIdx.x * 32, r0 = blockIdx.y * 32;
  int row = threadIdx.x >> 3, c4 = (threadIdx.x & 7) * 4;
  float4 v = *(const float4*)(src + (size_t)(r0 + row) * C + c0 + c4);
  t[row][c4 + 0] = v.x; t[row][c4 + 1] = v.y; t[row][c4 + 2] = v.z; t[row][c4 + 3] = v.w;
  __syncthreads();
  ushortx4 oh, ol;
  #pragma unroll
  for (int i = 0; i < 4; ++i) {
    unsigned short hi, lo;
    split2(t[c4 + i][row], hi, lo);
    oh[i] = hi; ol[i] = lo;
  }
  size_t didx = (size_t)(c0 + row) * R + r0 + c4;
  *(ushortx4*)(dhi + didx) = oh;
  *(ushortx4*)(dlo + didx) = ol;
}

// -------- fused QKV transpose+split into packed [3072][2048]: x<64 Q, <80 K, else V --------
__global__ __launch_bounds__(256) void tsplit_qkv_kernel(const float* __restrict__ q_w,
                                                         const float* __restrict__ k_w,
                                                         const float* __restrict__ v_w,
                                                         unsigned short* __restrict__ dhi,
                                                         unsigned short* __restrict__ dlo) {
  int bx = blockIdx.x;
  const float* src; int C, roff, c0;
  if (bx < 64)      { src = q_w; C = 2048; roff = 0;    c0 = bx * 32; }
  else if (bx < 80) { src = k_w; C = 512;  roff = 2048; c0 = (bx - 64) * 32; }
  else              { src = v_w; C = 512;  roff = 2560; c0 = (bx - 80) * 32; }
  __shared__ float t[32][33];
  int r0 = blockIdx.y * 32;
  int row = threadIdx.x >> 3, c4 = (threadIdx.x & 7) * 4;
  float4 v = *(const float4*)(src + (size_t)(r0 + row) * C + c0 + c4);
  t[row][c4 + 0] = v.x; t[row][c4 + 1] = v.y; t[row][c4 + 2] = v.z; t[row][c4 + 3] = v.w;
  __syncthreads();
  ushortx4 oh, ol;
  #pragma unroll
  for (int i = 0; i < 4; ++i) {
    unsigned short hi, lo;
    split2(t[c4 + i][row], hi, lo);
    oh[i] = hi; ol[i] = lo;
  }
  size_t didx = (size_t)(roff + c0 + row) * 2048 + r0 + c4;
  *(ushortx4*)(dhi + didx) = oh;
  *(ushortx4*)(dlo + didx) = ol;
}

// ---------------- RMSNorm. MODE 0: -> hi/lo bf16. MODE 1: -> fp32 + hi bf16 ----------------
template<int MODE>
__global__ __launch_bounds__(256) void rms_kernel(const float* __restrict__ in,
                                                  const float* __restrict__ sc,
                                                  float* __restrict__ outf,
                                                  unsigned short* __restrict__ o1,
                                                  unsigned short* __restrict__ o2) {
  __shared__ float red[4];
  int row = blockIdx.x, tid = threadIdx.x;
  const float4* x4 = (const float4*)(in + (size_t)row * D_);
  float4 a = x4[tid], b = x4[tid + 256];
  float ss = a.x*a.x + a.y*a.y + a.z*a.z + a.w*a.w
           + b.x*b.x + b.y*b.y + b.z*b.z + b.w*b.w;
  #pragma unroll
  for (int off = 1; off < 64; off <<= 1) ss += __shfl_xor(ss, off);
  if ((tid & 63) == 0) red[tid >> 6] = ss;
  __syncthreads();
  float r = rsqrtf((red[0] + red[1] + red[2] + red[3]) * (1.0f / D_) + 1e-6f);
  const float4* s4 = (const float4*)sc;
  float4 sa = s4[tid], sb = s4[tid + 256];
  float va[8] = { a.x*r*sa.x, a.y*r*sa.y, a.z*r*sa.z, a.w*r*sa.w,
                  b.x*r*sb.x, b.y*r*sb.y, b.z*r*sb.z, b.w*r*sb.w };
  if (MODE == 0) {
    ushortx4 h0, l0, h1, l1;
    #pragma unroll
    for (int i = 0; i < 4; ++i) { unsigned short h, l; split2(va[i], h, l); h0[i] = h; l0[i] = l; }
    #pragma unroll
    for (int i = 0; i < 4; ++i) { unsigned short h, l; split2(va[4 + i], h, l); h1[i] = h; l1[i] = l; }
    *(ushortx4*)(o1 + (size_t)row * D_ + tid * 4) = h0;
    *(ushortx4*)(o2 + (size_t)row * D_ + tid * 4) = l0;
    *(ushortx4*)(o1 + (size_t)row * D_ + 1024 + tid * 4) = h1;
    *(ushortx4*)(o2 + (size_t)row * D_ + 1024 + tid * 4) = l1;
  } else {
    *(float4*)(outf + (size_t)row * D_ + tid * 4) = make_float4(va[0], va[1], va[2], va[3]);
    *(float4*)(outf + (size_t)row * D_ + 1024 + tid * 4) = make_float4(va[4], va[5], va[6], va[7]);
    ushortx4 h0 = { f2bf(va[0]), f2bf(va[1]), f2bf(va[2]), f2bf(va[3]) };
    ushortx4 h1 = { f2bf(va[4]), f2bf(va[5]), f2bf(va[6]), f2bf(va[7]) };
    *(ushortx4*)(o1 + (size_t)row * D_ + tid * 4) = h0;
    *(ushortx4*)(o1 + (size_t)row * D_ + 1024 + tid * 4) = h1;
  }
}

// ---------------- split GEMM 128-tile, gload_lds + XOR swizzle + 2-phase dbuf ----------------
template<int EPI>
__global__ __launch_bounds__(256) void gemm_bb128g(const unsigned short* __restrict__ Ahi,
                                                   const unsigned short* __restrict__ Alo,
                                                   const unsigned short* __restrict__ Bhi,
                                                   const unsigned short* __restrict__ Blo,
                                                   const float* __restrict__ res,
                                                   float* __restrict__ out,
                                                   int M, int Nn, int K) {
  int g = blockIdx.x;
  int nwg = gridDim.x;
  int per = nwg >> 3;
  int sw = (g & 7) * per + (g >> 3);
  int my = M >> 7;
  int xt = sw / my, yt = sw - xt * my;
  int m0 = yt * 128, n0 = xt * 128;
  __shared__ unsigned short Ah[2][128 * 32], Al[2][128 * 32];
  __shared__ unsigned short Bh[2][128 * 32], Bl[2][128 * 32];
  int tid = threadIdx.x, l = tid & 63, wid = tid >> 6;
  int lr = l & 15, lk = (l >> 4) * 8;
  int wr = (wid >> 1) * 64, wc = (wid & 1) * 64;
  int srl = l >> 2;
  int sch = ((l & 3) ^ (srl & 3)) * 8;
  size_t aoffs[2], boffs[2];
  int ldo[2];
  #pragma unroll
  for (int i = 0; i < 2; ++i) {
    int r = wid * 32 + i * 16 + srl;
    aoffs[i] = (size_t)(m0 + r) * K + sch;
    boffs[i] = (size_t)(n0 + r) * K + sch;
    ldo[i] = (wid * 32 + i * 16) * 32;
  }
  floatx4 acc[4][4];
  #pragma unroll
  for (int i = 0; i < 4; ++i)
    #pragma unroll
    for (int j = 0; j < 4; ++j) acc[i][j] = (floatx4){0.f, 0.f, 0.f, 0.f};

  auto stage = [&](int sel, int k0) {
    #pragma unroll
    for (int i = 0; i < 2; ++i) {
      gload16(Ahi + aoffs[i] + k0, &Ah[sel][ldo[i]]);
      gload16(Alo + aoffs[i] + k0, &Al[sel][ldo[i]]);
      gload16(Bhi + boffs[i] + k0, &Bh[sel][ldo[i]]);
      gload16(Blo + boffs[i] + k0, &Bl[sel][ldo[i]]);
    }
  };

  int rsw = ((l >> 4) ^ (lr & 3)) << 3;
  stage(0, 0);
  asm volatile("s_waitcnt vmcnt(0)" ::: "memory");
  __syncthreads();
  for (int k0 = 0; k0 < K; k0 += 32) {
    int cur = (k0 >> 5) & 1;
    if (k0 + 32 < K) stage(cur ^ 1, k0 + 32);
    short8 ah[4], al_[4];
    #pragma unroll
    for (int i = 0; i < 4; ++i) {
      int ao = (wr + i * 16 + lr) * 32 + rsw;
      ah[i]  = *(const short8*)&Ah[cur][ao];
      al_[i] = *(const short8*)&Al[cur][ao];
    }
    #pragma unroll
    for (int j = 0; j < 4; ++j) {
      int bo = (wc + j * 16 + lr) * 32 + rsw;
      short8 bh  = *(const short8*)&Bh[cur][bo];
      short8 bl_ = *(const short8*)&Bl[cur][bo];
      #pragma unroll
      for (int i = 0; i < 4; ++i) {
        acc[i][j] = __builtin_amdgcn_mfma_f32_16x16x32_bf16(ah[i], bh, acc[i][j], 0, 0, 0);
        acc[i][j] = __builtin_amdgcn_mfma_f32_16x16x32_bf16(ah[i], bl_, acc[i][j], 0, 0, 0);
        acc[i][j] = __builtin_amdgcn_mfma_f32_16x16x32_bf16(al_[i], bh, acc[i][j], 0, 0, 0);
      }
    }
    asm volatile("s_waitcnt vmcnt(0)" ::: "memory");
    __syncthreads();
  }
  int rq = (l >> 4) * 4;
  #pragma unroll
  for (int i = 0; i < 4; ++i)
    #pragma unroll
    for (int j = 0; j < 4; ++j)
      #pragma unroll
      for (int r = 0; r < 4; ++r) {
        size_t idx = (size_t)(m0 + wr + i * 16 + rq + r) * Nn + (n0 + wc + j * 16 + lr);
        float v = acc[i][j][r];
        if (EPI == 1) v += res[idx];
        out[idx] = v;
      }
}

// ---------------- per-head RMSNorm + RoPE -> split bf16 q/k ----------------
// qkvb: [NT][3072] fp32 packed (q at h*128, k at 2048+kvh*128, v at 2560+kvh*128)
__global__ __launch_bounds__(256) void qknorm_rope_kernel(const float* __restrict__ qkvb,
                                                          const float* __restrict__ qs,
                                                          const float* __restrict__ ks,
                                                          unsigned short* __restrict__ qhi,
                                                          unsigned short* __restrict__ qlo,
                                                          unsigned short* __restrict__ khi,
                                                          unsigned short* __restrict__ klo) {
  int gw = blockIdx.x * 4 + (threadIdx.x >> 6);
  int l = threadIdx.x & 63;
  const float* ptr; const float* sc; unsigned short *dhi, *dlo; int t;
  size_t orow;
  if (gw < NT_ * H_) {
    t = gw >> 4;
    ptr = qkvb + (size_t)t * 3072 + (gw & 15) * HD_;
    sc = qs; dhi = qhi; dlo = qlo; orow = (size_t)gw * HD_;
  } else {
    int r = gw - NT_ * H_;
    t = r >> 2;
    ptr = qkvb + (size_t)t * 3072 + 2048 + (r & 3) * HD_;
    sc = ks; dhi = khi; dlo = klo; orow = (size_t)r * HD_;
  }
  int pos = t & (SS_ - 1);
  float2 x = *(const float2*)(ptr + 2 * l);
  float p2 = x.x * x.x + x.y * x.y;
  #pragma unroll
  for (int off = 1; off < 64; off <<= 1) p2 += __shfl_xor(p2, off);
  float rms = rsqrtf(p2 * (1.0f / HD_) + 1e-6f);
  float nx = x.x * rms * sc[2 * l];
  float ny = x.y * rms * sc[2 * l + 1];
  int j0 = (2 * l) & 63;
  float ang0 = pos * __expf(-(float)j0 * (13.815510557964274f / 64.0f));
  float ang1 = pos * __expf(-(float)(j0 + 1) * (13.815510557964274f / 64.0f));
  float s0, c0, s1, c1;
  sincosf(ang0, &s0, &c0);
  sincosf(ang1, &s1, &c1);
  float ox = __shfl_xor(nx, 32);
  float oy = __shfl_xor(ny, 32);
  float r0, r1;
  if (l < 32) { r0 = nx * c0 - ox * s0; r1 = ny * c1 - oy * s1; }
  else        { r0 = nx * c0 + ox * s0; r1 = ny * c1 + oy * s1; }
  unsigned short h0, l0, h1, l1;
  split2(r0, h0, l0);
  split2(r1, h1, l1);
  *(unsigned*)(dhi + orow + 2 * l) = (unsigned)h0 | ((unsigned)h1 << 16);
  *(unsigned*)(dlo + orow + 2 * l) = (unsigned)l0 | ((unsigned)l1 << 16);
}

// ---------------- V split + transpose: packed qkvb [NT][3072] -> hi/lo bf16 [b kvh d s] ------
__global__ __launch_bounds__(256) void vsplit_kernel(const float* __restrict__ qkvb,
                                                     unsigned short* __restrict__ vthi,
                                                     unsigned short* __restrict__ vtlo) {
  int d0 = blockIdx.x * 32, s0 = blockIdx.y * 32, bk = blockIdx.z;
  int b = bk >> 2, kvh = bk & 3;
  __shared__ float t[32][33];
  int row = threadIdx.x >> 3, c4 = (threadIdx.x & 7) * 4;
  float4 v = *(const float4*)(qkvb + (size_t)(b * SS_ + s0 + row) * 3072 + 2560 + kvh * HD_ + d0 + c4);
  t[row][c4 + 0] = v.x; t[row][c4 + 1] = v.y; t[row][c4 + 2] = v.z; t[row][c4 + 3] = v.w;
  __syncthreads();
  ushortx4 oh, ol;
  #pragma unroll
  for (int i = 0; i < 4; ++i) {
    unsigned short hi, lo;
    split2(t[c4 + i][row], hi, lo);
    oh[i] = hi; ol[i] = lo;
  }
  size_t idx = ((size_t)(b * KVH_ + kvh) * HD_ + d0 + row) * SS_ + s0 + c4;
  *(ushortx4*)(vthi + idx) = oh;
  *(ushortx4*)(vtlo + idx) = ol;
}

// ---------------- MFMA flash attention: LDS-staged KV, 2-phase dbuf prefetch ----------------
// Co-resident block pairs differ by blockIdx.z (stride-256 round-robin), so batch 1 runs the
// reversed qt order: per-CU causal work = (2x+2)+(2(15-x)+2) = 34 tiles, uniform.
__global__ __launch_bounds__(256) void attn_kernel(const unsigned short* __restrict__ qhi,
                                                   const unsigned short* __restrict__ qlo,
                                                   const unsigned short* __restrict__ khi,
                                                   const unsigned short* __restrict__ klo,
                                                   const unsigned short* __restrict__ vthi,
                                                   const unsigned short* __restrict__ vtlo,
                                                   unsigned short* __restrict__ ctx_hi,
                                                   unsigned short* __restrict__ ctx_lo) {
  int qtx = blockIdx.x, h = blockIdx.y, b = blockIdx.z;
  int qt = (b & 1) ? ((int)gridDim.x - 1 - qtx) : qtx;
  int kvh = h >> 2;
  int tid = threadIdx.x, l = tid & 63, wid = tid >> 6;
  int lr = l & 15, lk = (l >> 4) * 8;
  __shared__ unsigned short Kh[2][32 * 128], Kl[2][32 * 128];
  __shared__ unsigned short Vh[2][128 * 32], Vl[2][128 * 32];
  __shared__ unsigned short Ph[64 * 40], Pl[64 * 40];
  int qt0 = qt * 64;

  size_t qrow = ((size_t)((b * SS_ + qt0 + wid * 16 + lr) * H_) + h) * HD_;
  short8 qfh[4], qfl[4];
  #pragma unroll
  for (int t = 0; t < 4; ++t) {
    qfh[t] = *(const short8*)(qhi + qrow + t * 32 + lk);
    qfl[t] = *(const short8*)(qlo + qrow + t * 32 + lk);
  }

  float m[4], sum[4];
  #pragma unroll
  for (int r = 0; r < 4; ++r) { m[r] = -__builtin_inff(); sum[r] = 0.f; }
  floatx4 o[8];
  #pragma unroll
  for (int cb = 0; cb < 8; ++cb) o[cb] = (floatx4){0.f, 0.f, 0.f, 0.f};

  size_t vbase = ((size_t)(b * KVH_ + kvh) * HD_) * SS_;
  int nt = 2 * qt + 2;

  auto stage = [&](int sel, int kt) {
    int k0 = kt * 32;
    #pragma unroll
    for (int i = 0; i < 2; ++i) {
      int r = wid * 8 + i * 4 + (l >> 4);
      int ch = (l & 15) ^ (r & 7);
      size_t gk = ((size_t)((b * SS_ + k0 + r) * KVH_) + kvh) * HD_ + ch * 8;
      gload16(khi + gk, &Kh[sel][(wid * 8 + i * 4) * 128]);
      gload16(klo + gk, &Kl[sel][(wid * 8 + i * 4) * 128]);
    }
    #pragma unroll
    for (int i = 0; i < 2; ++i) {
      int r = wid * 32 + i * 16 + (l >> 2);
      int ch = (l & 3) ^ (r & 3);
      size_t gv = vbase + (size_t)r * SS_ + k0 + ch * 8;
      gload16(vthi + gv, &Vh[sel][(wid * 32 + i * 16) * 32]);
      gload16(vtlo + gv, &Vl[sel][(wid * 32 + i * 16) * 32]);
    }
  };

  stage(0, 0);
  asm volatile("s_waitcnt vmcnt(0)" ::: "memory");
  __syncthreads();

  for (int kt = 0; kt < nt; ++kt) {
    int cur = kt & 1;
    if (kt + 1 < nt) stage(cur ^ 1, kt + 1);
    int k0 = kt * 32;
    float sv[2][4];
    #pragma unroll
    for (int kbk = 0; kbk < 2; ++kbk) {
      int kr = kbk * 16 + lr;
      floatx4 s = (floatx4){0.f, 0.f, 0.f, 0.f};
      #pragma unroll
      for (int t = 0; t < 4; ++t) {
        int co = kr * 128 + (((t * 4 + (l >> 4)) ^ (lr & 7)) << 3);
        short8 kfh = *(const short8*)&Kh[cur][co];
        short8 kfl = *(const short8*)&Kl[cur][co];
        s = __builtin_amdgcn_mfma_f32_16x16x32_bf16(qfh[t], kfh, s, 0, 0, 0);
        s = __builtin_amdgcn_mfma_f32_16x16x32_bf16(qfh[t], kfl, s, 0, 0, 0);
        s = __builtin_amdgcn_mfma_f32_16x16x32_bf16(qfl[t], kfh, s, 0, 0, 0);
      }
      int key = k0 + kr;
      #pragma unroll
      for (int r = 0; r < 4; ++r) {
        int q = qt0 + wid * 16 + (l >> 4) * 4 + r;
        float x = s[r] * 0.08838834764831845f;
        sv[kbk][r] = (key <= q) ? x : -1e30f;
      }
    }
    float f[4], p[2][4];
    #pragma unroll
    for (int r = 0; r < 4; ++r) {
      float tm = fmaxf(sv[0][r], sv[1][r]);
      tm = fmaxf(tm, __shfl_xor(tm, 1));
      tm = fmaxf(tm, __shfl_xor(tm, 2));
      tm = fmaxf(tm, __shfl_xor(tm, 4));
      tm = fmaxf(tm, __shfl_xor(tm, 8));
      float mn = fmaxf(m[r], tm);
      f[r] = __expf(m[r] - mn);
      m[r] = mn;
      float rs = 0.f;
      #pragma unroll
      for (int kbk = 0; kbk < 2; ++kbk) { p[kbk][r] = __expf(sv[kbk][r] - mn); rs += p[kbk][r]; }
      rs += __shfl_xor(rs, 1); rs += __shfl_xor(rs, 2);
      rs += __shfl_xor(rs, 4); rs += __shfl_xor(rs, 8);
      sum[r] = sum[r] * f[r] + rs;
    }
    #pragma unroll
    for (int kbk = 0; kbk < 2; ++kbk)
      #pragma unroll
      for (int r = 0; r < 4; ++r)
        split2(p[kbk][r],
               Ph[(wid * 16 + (l >> 4) * 4 + r) * 40 + kbk * 16 + lr],
               Pl[(wid * 16 + (l >> 4) * 4 + r) * 40 + kbk * 16 + lr]);
    #pragma unroll
    for (int cb = 0; cb < 8; ++cb)
      #pragma unroll
      for (int r = 0; r < 4; ++r) o[cb][r] = o[cb][r] * f[r];
    int pco = (wid * 16 + lr) * 40 + lk;
    short8 pah = *(const short8*)&Ph[pco];
    short8 pal = *(const short8*)&Pl[pco];
    #pragma unroll
    for (int cb = 0; cb < 8; ++cb) {
      int vo = (cb * 16 + lr) * 32 + (((l >> 4) ^ (lr & 3)) << 3);
      short8 vbh = *(const short8*)&Vh[cur][vo];
      short8 vbl = *(const short8*)&Vl[cur][vo];
      o[cb] = __builtin_amdgcn_mfma_f32_16x16x32_bf16(pah, vbh, o[cb], 0, 0, 0);
      o[cb] = __builtin_amdgcn_mfma_f32_16x16x32_bf16(pah, vbl, o[cb], 0, 0, 0);
      o[cb] = __builtin_amdgcn_mfma_f32_16x16x32_bf16(pal, vbh, o[cb], 0, 0, 0);
    }
    asm volatile("s_waitcnt vmcnt(0)" ::: "memory");
    __syncthreads();
  }
  #pragma unroll
  for (int cb = 0; cb < 8; ++cb)
    #pragma unroll
    for (int r = 0; r < 4; ++r) {
      int q = qt0 + wid * 16 + (l >> 4) * 4 + r;
      int d = cb * 16 + lr;
      float val = o[cb][r] / sum[r];
      unsigned short hi, lo;
      split2(val, hi, lo);
      size_t idx = ((size_t)(b * SS_ + q)) * (H_ * HD_) + h * HD_ + d;
      ctx_hi[idx] = hi;
      ctx_lo[idx] = lo;
    }
}

// ---------------- Router (fp32) ----------------
__global__ __launch_bounds__(256) void router_kernel(const float* __restrict__ x2,
                                                     const float* __restrict__ gw,
                                                     float* __restrict__ logits) {
  int t = blockIdx.x * 4 + (threadIdx.x >> 6);
  int l = threadIdx.x & 63;
  float acc[32];
  #pragma unroll
  for (int e = 0; e < 32; ++e) acc[e] = 0.f;
  for (int i = 0; i < 32; ++i) {
    int d = i * 64 + l;
    float xv = x2[(size_t)t * D_ + d];
    const float4* wr = (const float4*)(gw + (size_t)d * E_);
    #pragma unroll
    for (int j = 0; j < 8; ++j) {
      float4 wv = wr[j];
      acc[4 * j + 0] += xv * wv.x; acc[4 * j + 1] += xv * wv.y;
      acc[4 * j + 2] += xv * wv.z; acc[4 * j + 3] += xv * wv.w;
    }
  }
  #pragma unroll
  for (int e = 0; e < 32; ++e) {
    acc[e] += __shfl_xor(acc[e], 1);  acc[e] += __shfl_xor(acc[e], 2);
    acc[e] += __shfl_xor(acc[e], 4);  acc[e] += __shfl_xor(acc[e], 8);
    acc[e] += __shfl_xor(acc[e], 16); acc[e] += __shfl_xor(acc[e], 32);
  }
  if (l == 0) {
    #pragma unroll
    for (int e = 0; e < 32; ++e) logits[(size_t)t * E_ + e] = acc[e];
  }
}

// ---------------- top-8 + softmax + expert counting ----------------
__global__ void topk_kernel(const float* __restrict__ logits, int* __restrict__ sel,
                            float* __restrict__ wts, int* __restrict__ counts) {
  int t = blockIdx.x * blockDim.x + threadIdx.x;
  if (t >= NT_) return;
  float v[32];
  for (int e = 0; e < 32; ++e) v[e] = logits[(size_t)t * E_ + e];
  float val[8]; int idx[8];
  for (int k = 0; k < 8; ++k) {
    float best = -__builtin_inff(); int bi = 0;
    for (int e = 0; e < 32; ++e) if (v[e] > best) { best = v[e]; bi = e; }
    val[k] = best; idx[k] = bi; v[bi] = -__builtin_inff();
  }
  float mx = val[0], s = 0.f; float ex[8];
  for (int k = 0; k < 8; ++k) { ex[k] = expf(val[k] - mx); s += ex[k]; }
  float inv = 1.f / s;
  for (int k = 0; k < 8; ++k) {
    sel[t * 8 + k] = idx[k];
    wts[t * 8 + k] = ex[k] * inv;
    atomicAdd(&counts[idx[k]], 1);
  }
}

__global__ void scan_kernel(const int* __restrict__ counts, int* __restrict__ offs,
                            int* __restrict__ cursors) {
  if (threadIdx.x == 0) {
    int c = 0;
    for (int e = 0; e < E_; ++e) { offs[e] = c; cursors[e] = c; c += counts[e]; }
  }
}

__global__ void scatter_kernel(const int* __restrict__ sel, const float* __restrict__ wts,
                               int* __restrict__ cursors, int* __restrict__ pair_t,
                               float* __restrict__ pair_w, int* __restrict__ pos) {
  int g = blockIdx.x * blockDim.x + threadIdx.x;
  if (g >= NPAIR_) return;
  int e = sel[g];
  int p = atomicAdd(&cursors[e], 1);
  pair_t[p] = g >> 3;
  pair_w[p] = wts[g];
  pos[g] = p;
}

// ---------------- gate+up expert GEMM: 4-wave 128x(64G+64U), BK=32, 3-stage counted vmcnt ----
__global__ __launch_bounds__(256, 3) void gateup_kernel(const unsigned short* __restrict__ xbf,
                                                        const unsigned short* __restrict__ gT,
                                                        const unsigned short* __restrict__ uT,
                                                        const int* __restrict__ counts,
                                                        const int* __restrict__ offs,
                                                        const int* __restrict__ pair_t,
                                                        const float* __restrict__ pair_w,
                                                        unsigned short* __restrict__ act) {
  int g = blockIdx.x;
  int lg = (g & ~127) | (((g & 7) << 4) | ((g >> 3) & 15));
  int e = lg / 192;                       // 12 xt * 16 yt per expert
  int rem = lg - e * 192;
  int xt = rem >> 4, yt = rem & 15;
  int cnt = counts[e];
  int r0 = yt * 128;
  if (r0 >= cnt) return;
  int base = offs[e];
  int n0 = xt * 64;
  const unsigned short* G = gT + (size_t)e * F_ * D_;
  const unsigned short* U = uT + (size_t)e * F_ * D_;
  __shared__ unsigned short As[3][128 * 32], Gs[3][64 * 32], Us[3][64 * 32];   // 48 KB
  int tid = threadIdx.x, l = tid & 63, wid = tid >> 6;   // 4 waves
  int lr = l & 15, lk16 = l >> 4;
  int srl = l >> 2;                            // staging row-in-16
  int sch = ((l & 3) ^ ((srl >> 1) & 3)) * 8;  // conflict-free XOR (matches read side)
  const unsigned short* asrc[2];
  #pragma unroll
  for (int i = 0; i < 2; ++i) {
    int rowt = wid * 32 + i * 16 + srl;
    int cr = r0 + rowt; if (cr > cnt - 1) cr = cnt - 1;
    asrc[i] = xbf + (size_t)pair_t[base + cr] * D_ + sch;
  }
  const unsigned short* gsrc = G + (size_t)(n0 + wid * 16 + srl) * D_ + sch;
  const unsigned short* usrc = U + (size_t)(n0 + wid * 16 + srl) * D_ + sch;
  int wm = wid >> 1;    // 0..1 -> 64 rows
  int wn = wid & 1;     // 0..1 -> 32 cols of G and U
  floatx4 ag[4][2], au[4][2];
  #pragma unroll
  for (int i = 0; i < 4; ++i)
    #pragma unroll
    for (int j = 0; j < 2; ++j) { ag[i][j] = (floatx4){0.f,0.f,0.f,0.f}; au[i][j] = (floatx4){0.f,0.f,0.f,0.f}; }

  auto stage = [&](int sel, int kofs) {    // 4 loads per lane
    gload16(asrc[0] + kofs, &As[sel][(wid * 32) * 32]);
    gload16(asrc[1] + kofs, &As[sel][(wid * 32 + 16) * 32]);
    gload16(gsrc + kofs, &Gs[sel][(wid * 16) * 32]);
    gload16(usrc + kofs, &Us[sel][(wid * 16) * 32]);
  };

  const int nt = D_ / 32;   // 64
  stage(0, 0);
  stage(1, 32);
  for (int t = 0; t < nt; ++t) {
    int cur = t % 3;
    if (t + 1 < nt) { asm volatile("s_waitcnt vmcnt(4)" ::: "memory"); }
    else            { asm volatile("s_waitcnt vmcnt(0)" ::: "memory"); }
    __builtin_amdgcn_sched_barrier(0);
    __syncthreads();                      // all waves past iter t-1 reads of buf (t+2)%3
    if (t + 2 < nt) stage((t + 2) % 3, (t + 2) * 32);
    int co = (lk16 ^ ((lr >> 1) & 3)) << 3;
    short8 a[4], gg[2], uu[2];
    #pragma unroll
    for (int i = 0; i < 4; ++i)
      a[i] = *(const short8*)&As[cur][(wm * 64 + i * 16 + lr) * 32 + co];
    #pragma unroll
    for (int j = 0; j < 2; ++j) {
      gg[j] = *(const short8*)&Gs[cur][(wn * 32 + j * 16 + lr) * 32 + co];
      uu[j] = *(const short8*)&Us[cur][(wn * 32 + j * 16 + lr) * 32 + co];
    }
    __builtin_amdgcn_s_setprio(1);
    #pragma unroll
    for (int i = 0; i < 4; ++i)
      #pragma unroll
      for (int j = 0; j < 2; ++j) {
        ag[i][j] = __builtin_amdgcn_mfma_f32_16x16x32_bf16(a[i], gg[j], ag[i][j], 0, 0, 0);
        au[i][j] = __builtin_amdgcn_mfma_f32_16x16x32_bf16(a[i], uu[j], au[i][j], 0, 0, 0);
      }
    __builtin_amdgcn_s_setprio(0);
  }
  int rq = (l >> 4) * 4;
  #pragma unroll
  for (int i = 0; i < 4; ++i)
    #pragma unroll
    for (int r = 0; r < 4; ++r) {
      int rowl = wm * 64 + i * 16 + rq + r;
      if (r0 + rowl < cnt) {
        int p = base + r0 + rowl;
        float pw = pair_w[p];
        size_t orow = (size_t)p * F_;
        #pragma unroll
        for (int j = 0; j < 2; ++j) {
          float gv = ag[i][j][r], uv = au[i][j][r];
          float a = (gv / (1.f + __expf(-gv))) * uv * pw;
          act[orow + n0 + wn * 32 + j * 16 + lr] = f2bf(a);
        }
      }
    }
}

// ---------------- down expert GEMM: 4-wave 128x128, BK=32, 3-stage counted vmcnt, bf16 out ----
__global__ __launch_bounds__(256, 3) void down_kernel(const unsigned short* __restrict__ act,
                                                      const unsigned short* __restrict__ dT,
                                                      const int* __restrict__ counts,
                                                      const int* __restrict__ offs,
                                                      unsigned short* __restrict__ dpre) {
  int g = blockIdx.x;
  int lg = (g & ~255) | (((g & 7) << 5) | ((g >> 3) & 31));
  int e = lg >> 8;                     // 16 xt * 16 yt per expert
  int rem = lg & 255;
  int xt = rem >> 4, yt = rem & 15;
  int cnt = counts[e];
  int r0 = yt * 128;
  if (r0 >= cnt) return;
  int base = offs[e];
  int n0 = xt * 128;
  const unsigned short* B = dT + (size_t)e * ((size_t)D_ * F_);
  __shared__ unsigned short As[3][128 * 32], Bs[3][128 * 32];   // 48 KB
  int tid = threadIdx.x, l = tid & 63, wid = tid >> 6;
  int lr = l & 15, lk16 = l >> 4;
  int srl = l >> 2;
  int sch = ((l & 3) ^ ((srl >> 1) & 3)) * 8;
  const unsigned short* asrc[2];
  const unsigned short* bsrc[2];
  #pragma unroll
  for (int i = 0; i < 2; ++i) {
    int rowt = wid * 32 + i * 16 + srl;
    int cr = r0 + rowt; if (cr > cnt - 1) cr = cnt - 1;
    asrc[i] = act + (size_t)(base + cr) * F_ + sch;
    bsrc[i] = B + (size_t)(n0 + rowt) * F_ + sch;
  }
  int wm = wid >> 1;    // 0..1 -> 64 rows
  int wn = wid & 1;     // 0..1 -> 64 cols
  floatx4 acc[4][4];
  #pragma unroll
  for (int i = 0; i < 4; ++i)
    #pragma unroll
    for (int j = 0; j < 4; ++j) acc[i][j] = (floatx4){0.f, 0.f, 0.f, 0.f};

  auto stage = [&](int sel, int kofs) {    // 4 loads per lane
    gload16(asrc[0] + kofs, &As[sel][(wid * 32) * 32]);
    gload16(asrc[1] + kofs, &As[sel][(wid * 32 + 16) * 32]);
    gload16(bsrc[0] + kofs, &Bs[sel][(wid * 32) * 32]);
    gload16(bsrc[1] + kofs, &Bs[sel][(wid * 32 + 16) * 32]);
  };

  const int nt = F_ / 32;   // 24
  stage(0, 0);
  stage(1, 32);
  for (int t = 0; t < nt; ++t) {
    int cur = t % 3;
    if (t + 1 < nt) { asm volatile("s_waitcnt vmcnt(4)" ::: "memory"); }
    else            { asm volatile("s_waitcnt vmcnt(0)" ::: "memory"); }
    __builtin_amdgcn_sched_barrier(0);
    __syncthreads();
    if (t + 2 < nt) stage((t + 2) % 3, (t + 2) * 32);
    int co = (lk16 ^ ((lr >> 1) & 3)) << 3;
    short8 a[4], b_[4];
    #pragma unroll
    for (int i = 0; i < 4; ++i) {
      a[i]  = *(const short8*)&As[cur][(wm * 64 + i * 16 + lr) * 32 + co];
      b_[i] = *(const short8*)&Bs[cur][(wn * 64 + i * 16 + lr) * 32 + co];
    }
    __builtin_amdgcn_s_setprio(1);
    #pragma unroll
    for (int i = 0; i < 4; ++i)
      #pragma unroll
      for (int j = 0; j < 4; ++j)
        acc[i][j] = __builtin_amdgcn_mfma_f32_16x16x32_bf16(a[i], b_[j], acc[i][j], 0, 0, 0);
    __builtin_amdgcn_s_setprio(0);
  }
  int rq = (l >> 4) * 4;
  #pragma unroll
  for (int i = 0; i < 4; ++i)
    #pragma unroll
    for (int r = 0; r < 4; ++r) {
      int rowl = wm * 64 + i * 16 + rq + r;
      if (r0 + rowl < cnt) {
        size_t orow = (size_t)(base + r0 + rowl) * D_;
        #pragma unroll
        for (int j = 0; j < 4; ++j)
          dpre[orow + n0 + wn * 64 + j * 16 + lr] = f2bf(acc[i][j][r]);
      }
    }
}

// ---------------- MoE gather: out[t] += sum_k dpre_bf16[pos[t*8+k]] ----------------
__global__ __launch_bounds__(256) void moe_gather_kernel(const unsigned short* __restrict__ dpre,
                                                         const int* __restrict__ pos,
                                                         float* __restrict__ out) {
  int t = blockIdx.x;
  int tid = threadIdx.x;
  int p[8];
  #pragma unroll
  for (int k = 0; k < 8; ++k) p[k] = pos[t * 8 + k];
  size_t orow = (size_t)t * D_;
  int col = tid * 8;
  float s[8];
  float4 o0 = *(const float4*)(out + orow + col);
  float4 o1 = *(const float4*)(out + orow + col + 4);
  s[0] = o0.x; s[1] = o0.y; s[2] = o0.z; s[3] = o0.w;
  s[4] = o1.x; s[5] = o1.y; s[6] = o1.z; s[7] = o1.w;
  #pragma unroll
  for (int k = 0; k < 8; ++k) {
    short8 v = *(const short8*)(dpre + (size_t)p[k] * D_ + col);
    #pragma unroll
    for (int j = 0; j < 8; ++j) s[j] += bf2f((unsigned short)v[j]);
  }
  *(float4*)(out + orow + col) = make_float4(s[0], s[1], s[2], s[3]);
  *(float4*)(out + orow + col + 4) = make_float4(s[4], s[5], s[6], s[7]);
}

// ---------------- launch ----------------
extern "C" void kernel_launch(void* const* d_in, const int* in_sizes, int n_in,
                              void* d_out, int out_size, void* d_ws, size_t ws_size,
                              hipStream_t stream) {
  const float* hidden  = (const float*)d_in[0];
  const float* in_ln   = (const float*)d_in[2];
  const float* post_ln = (const float*)d_in[3];
  const float* q_w     = (const float*)d_in[4];
  const float* k_w     = (const float*)d_in[5];
  const float* v_w     = (const float*)d_in[6];
  const float* o_w     = (const float*)d_in[7];
  const float* q_ns    = (const float*)d_in[8];
  const float* k_ns    = (const float*)d_in[9];
  const float* gate_w  = (const float*)d_in[10];
  const float* gate_p  = (const float*)d_in[11];
  const float* up_p    = (const float*)d_in[12];
  const float* down_p  = (const float*)d_in[13];
  float* out = (float*)d_out;

  char* w = (char*)d_ws;
  size_t off = 0;
  auto alloc = [&](size_t b) { char* p = w + off; off += (b + 255) & ~(size_t)255; return p; };
  unsigned short* qkvThi = (unsigned short*)alloc((size_t)3072 * 2048 * 2);
  unsigned short* qkvTlo = (unsigned short*)alloc((size_t)3072 * 2048 * 2);
  unsigned short* oThi = (unsigned short*)alloc((size_t)2048 * 2048 * 2);
  unsigned short* oTlo = (unsigned short*)alloc((size_t)2048 * 2048 * 2);
  unsigned short* gT   = (unsigned short*)alloc((size_t)E_ * F_ * D_ * 2);
  unsigned short* uT   = (unsigned short*)alloc((size_t)E_ * F_ * D_ * 2);
  unsigned short* dT   = (unsigned short*)alloc((size_t)E_ * D_ * F_ * 2);
  unsigned short* h_hi = (unsigned short*)alloc((size_t)NT_ * D_ * 2);
  unsigned short* h_lo = (unsigned short*)alloc((size_t)NT_ * D_ * 2);
  float* qkvbuf = (float*)alloc((size_t)NT_ * 3072 * 4);
  unsigned short* qhi = (unsigned short*)alloc((size_t)NT_ * H_ * HD_ * 2);
  unsigned short* qlo = (unsigned short*)alloc((size_t)NT_ * H_ * HD_ * 2);
  unsigned short* khi = (unsigned short*)alloc((size_t)NT_ * KVH_ * HD_ * 2);
  unsigned short* klo = (unsigned short*)alloc((size_t)NT_ * KVH_ * HD_ * 2);
  unsigned short* vthi = (unsigned short*)alloc((size_t)NT_ * KVH_ * HD_ * 2);
  unsigned short* vtlo = (unsigned short*)alloc((size_t)NT_ * KVH_ * HD_ * 2);
  unsigned short* ctx_hi = (unsigned short*)alloc((size_t)NT_ * H_ * HD_ * 2);
  unsigned short* ctx_lo = (unsigned short*)alloc((size_t)NT_ * H_ * HD_ * 2);
  float* x2    = (float*)alloc((size_t)NT_ * D_ * 4);
  unsigned short* x2bf = (unsigned short*)alloc((size_t)NT_ * D_ * 2);
  float* logits = (float*)alloc((size_t)NT_ * E_ * 4);
  int*   sel    = (int*)alloc((size_t)NT_ * TOPK_ * 4);
  float* wts    = (float*)alloc((size_t)NT_ * TOPK_ * 4);
  int*   counts = (int*)alloc(E_ * 4);
  int*   offs   = (int*)alloc(E_ * 4);
  int*   curs   = (int*)alloc(E_ * 4);
  int*   pair_t = (int*)alloc((size_t)NPAIR_ * 4);
  float* pair_w = (float*)alloc((size_t)NPAIR_ * 4);
  int*   pos    = (int*)alloc((size_t)NPAIR_ * 4);
  unsigned short* act = (unsigned short*)alloc((size_t)NPAIR_ * F_ * 2);
  unsigned short* dpre = (unsigned short*)alloc((size_t)NPAIR_ * D_ * 2);

  // weight prep (Q, K, V transposed-split into one packed [3072][2048] matrix, single launch)
  tsplit_qkv_kernel<<<dim3(96, 64), 256, 0, stream>>>(q_w, k_w, v_w, qkvThi, qkvTlo);
  tsplit_kernel<<<dim3(64, 64), 256, 0, stream>>>(o_w, oThi, oTlo, 2048, 2048);
  tconv_gu_kernel<<<dim3(24, 64, 64), 256, 0, stream>>>(gate_p, up_p, gT, uT);
  tconv_kernel<<<dim3(64, 24, 32), 256, 0, stream>>>(down_p, dT, 768, 2048);

  rms_kernel<0><<<NT_, 256, 0, stream>>>(hidden, in_ln, nullptr, h_hi, h_lo);
  gemm_bb128g<0><<<384, 256, 0, stream>>>(h_hi, h_lo, qkvThi, qkvTlo, nullptr, qkvbuf, NT_, 3072, 2048);
  qknorm_rope_kernel<<<(NT_ * (H_ + KVH_)) / 4, 256, 0, stream>>>(qkvbuf, q_ns, k_ns,
                                                                  qhi, qlo, khi, klo);
  vsplit_kernel<<<dim3(HD_ / 32, SS_ / 32, NB_ * KVH_), 256, 0, stream>>>(qkvbuf, vthi, vtlo);
  attn_kernel<<<dim3(SS_ / 64, H_, NB_), 256, 0, stream>>>(qhi, qlo, khi, klo, vthi, vtlo,
                                                           ctx_hi, ctx_lo);
  gemm_bb128g<1><<<256, 256, 0, stream>>>(ctx_hi, ctx_lo, oThi, oTlo, hidden, out, NT_, 2048, 2048);
  rms_kernel<1><<<NT_, 256, 0, stream>>>(out, post_ln, x2, x2bf, nullptr);
  (void)hipMemsetAsync(counts, 0, E_ * 4, stream);
  router_kernel<<<NT_ / 4, 256, 0, stream>>>(x2, gate_w, logits);
  topk_kernel<<<NT_ / 256, 256, 0, stream>>>(logits, sel, wts, counts);
  scan_kernel<<<1, 64, 0, stream>>>(counts, offs, curs);
  scatter_kernel<<<NPAIR_ / 256, 256, 0, stream>>>(sel, wts, curs, pair_t, pair_w, pos);
  gateup_kernel<<<192 * 32, 256, 0, stream>>>(x2bf, gT, uT, counts, offs, pair_t, pair_w, act);
  down_kernel<<<256 * 32, 256, 0, stream>>>(act, dT, counts, offs, dpre);
  moe_gather_kernel<<<NT_, 256, 0, stream>>>(dpre, pos, out);
}